// Round 4
// baseline (954.910 us; speedup 1.0000x reference)
//
#include <hip/hip_runtime.h>
#include <hip/hip_bf16.h>

#define B_ 256
#define T_ 8
#define E_ 1024
#define H_ 1024
#define L_ 8
#define KD 2048   // E+H
#define ND 4096   // 4*H, gate-interleaved n = 4*j + g  (g: 0=u,1=f,2=o,3=c~)

#define BM 256
#define BN 128
#define BK 64
// per-buffer LDS: A 256x64 bf16 packed (32768 B) + B 128x64 bf16 (16384 B)
#define ABYTES 32768
#define BUFBYTES 49152
#define NT (KD / BK)   // 32 K-steps

typedef __bf16 bf16x8 __attribute__((ext_vector_type(8)));
typedef float floatx4 __attribute__((ext_vector_type(4)));

__device__ __forceinline__ float sigm(float x) { return 1.f / (1.f + __expf(-x)); }
__device__ __forceinline__ float tanh_(float x) { return 1.f - 2.f / (__expf(2.f * x) + 1.f); }

__device__ __forceinline__ void async16(const void* g, void* l) {
    __builtin_amdgcn_global_load_lds(
        (const __attribute__((address_space(1))) void*)g,
        (__attribute__((address_space(3))) void*)l, 16, 0, 0);
}

// ---------------------------------------------------------------------------
// P1 (per gate): W_g (L,2048,1024) fp32 -> WTt tiled bf16 layout:
//   WTt[l][nb(32)][kt(32)][row(128)][chunk(8)] , 16B chunks, where chunk slot
//   c stores original k-chunk (c ^ (row&7))  (pre-swizzled for the LDS reader).
// Each lstm_step B-stage is then one contiguous 16 KB block -> HBM streaming.
// ---------------------------------------------------------------------------
__global__ __launch_bounds__(256) void prep_weights_g(
    const float* __restrict__ src, __hip_bfloat16* __restrict__ WTt, int g)
{
    __shared__ float sm[64][33];
    int bid = blockIdx.x;
    int jt = bid & 31;          // 32 j-tiles of 32
    int kt = (bid >> 5) & 31;   // 32 k-tiles of 64
    int l  = bid >> 10;
    int tid = threadIdx.x;
    int j4  = tid & 7;          // float4 slot in row (8 per 32-float row)
    int kl0 = tid >> 3;         // 0..31
#pragma unroll
    for (int r = 0; r < 2; ++r) {
        int kl = kl0 + r * 32;  // 0..63
        float4 v = *(const float4*)&src[((size_t)(l * KD + kt * 64 + kl)) * 1024 + jt * 32 + j4 * 4];
        sm[kl][j4 * 4 + 0] = v.x;
        sm[kl][j4 * 4 + 1] = v.y;
        sm[kl][j4 * 4 + 2] = v.z;
        sm[kl][j4 * 4 + 3] = v.w;
    }
    __syncthreads();
    int jw = tid >> 3;          // 0..31
    int ch = tid & 7;           // original k-chunk index, kc = ch*8
    int kc = ch * 8;
    bf16x8 v;
#pragma unroll
    for (int i = 0; i < 8; ++i)
        v[i] = (__bf16)sm[kc + i][jw];
    int n   = jt * 32 + jw;     // original column j
    int nn  = n * 4 + g;        // gate-interleaved output row in [0,4096)
    int nb  = nn >> 7;
    int row = nn & 127;
    int cs  = ch ^ (row & 7);   // pre-swizzled chunk slot
    size_t off = ((((size_t)l * 32 + nb) * 32 + kt) * 128 + row) * 64 + (size_t)cs * 8;
    *(bf16x8*)&WTt[off] = v;
}

// ---------------------------------------------------------------------------
// P2: x -> bf16; h0 -> bf16; c0 -> fp32 cbuf; biases -> interleaved bcat
// ---------------------------------------------------------------------------
__global__ __launch_bounds__(256) void prep_misc(
    const float* __restrict__ x,  const float* __restrict__ h0,
    const float* __restrict__ c0,
    const float* __restrict__ bu, const float* __restrict__ bfv,
    const float* __restrict__ bo, const float* __restrict__ bc,
    __hip_bfloat16* __restrict__ xbf, __hip_bfloat16* __restrict__ hb0,
    float* __restrict__ cbuf, float* __restrict__ bcat)
{
    size_t i = (size_t)blockIdx.x * 256 + threadIdx.x;
    const size_t NX = (size_t)B_ * T_ * E_;
    const size_t NH = (size_t)L_ * B_ * H_;
    if (i < NX) {
        xbf[i] = __float2bfloat16(x[i]);
    } else if (i < NX + NH) {
        size_t j = i - NX; hb0[j] = __float2bfloat16(h0[j]);
    } else if (i < NX + 2 * NH) {
        size_t j = i - NX - NH; cbuf[j] = c0[j];
    } else if (i < NX + 2 * NH + (size_t)L_ * ND) {
        size_t j = i - NX - 2 * NH;
        int l = (int)(j >> 12); int n = (int)(j & 4095);
        int jj = n >> 2; int g = n & 3;
        const float* bs = (g == 0) ? bu : (g == 1) ? bfv : (g == 2) ? bo : bc;
        bcat[j] = bs[l * 1024 + jj];
    }
}

// ---------------------------------------------------------------------------
// One diagonal d = t + l. 32 blocks per cell (n_blk), BM=256 covers all batch.
// 512 threads = 8 waves (wave grid 4m x 2n, wave tile 64x64 of 16x16x32 MFMA).
// B-panel comes from the tiled WTt layout: each K-step's stage is a contiguous
// 16 KB block (per-thread addr = base + kt*16384 + s*8192 + tid*16).
// 3 LDS buffers, prefetch distance 2, counted vmcnt(6) once per K-step.
// ---------------------------------------------------------------------------
__global__ __launch_bounds__(512) void lstm_step(
    int d, int tmin,
    const __hip_bfloat16* __restrict__ xbf,
    const __hip_bfloat16* __restrict__ WTt,
    const float* __restrict__ bcat,
    __hip_bfloat16* __restrict__ hb0,
    __hip_bfloat16* __restrict__ hb1,
    float* __restrict__ cbuf,
    float* __restrict__ out)
{
    __shared__ __align__(16) char smraw[3][BUFBYTES];   // 147456 B

    int cell = blockIdx.x >> 5;
    int nb   = blockIdx.x & 31;
    int t = tmin + cell;
    int l = d - t;

    const __hip_bfloat16* hread  = (t & 1) ? hb1 : hb0;
    __hip_bfloat16*       hwrite = (t & 1) ? hb0 : hb1;

    const __hip_bfloat16* A1; int sA1;
    if (l == 0) { A1 = xbf + (size_t)t * E_;               sA1 = T_ * E_; }
    else        { A1 = hwrite + (size_t)(l - 1) * B_ * H_; sA1 = H_; }
    const __hip_bfloat16* A2 = hread + (size_t)l * B_ * H_;
    // tiled B panel base: WTt[l][nb][0][0][0]
    const __hip_bfloat16* Bt = WTt + (((size_t)l * 32 + nb) * 32) * 128 * 64;

    int tid  = threadIdx.x;
    int lane = tid & 63;
    int wid  = tid >> 6;
    int wm = (wid & 3) * 64;
    int wn = (wid >> 2) * 64;
    int lr   = lane & 15;
    int quad = lane >> 4;

    // ---- staging address precompute (fixed per thread across K) ----
    int srow = tid >> 3;                      // 0..63
    int c    = (tid & 7) ^ (srow & 7);        // XOR-swizzled 16B-chunk index (A)
    const __hip_bfloat16* pA1[4];
    const __hip_bfloat16* pA2[4];
#pragma unroll
    for (int s = 0; s < 4; ++s) {
        int row = s * 64 + srow;              // 0..255
        pA1[s] = A1 + (size_t)row * sA1 + c * 8;
        pA2[s] = A2 + (size_t)row * H_ + c * 8 - E_;
    }
    // B: linear stream, per-thread fixed offset tid*16 bytes within half-tile
    const __hip_bfloat16* pB0 = Bt + (size_t)tid * 8;
    int ldsWaveOff = wid * 1024;              // bytes

    auto stage = [&](int kt, int buf) {       // 6 global_load_lds per thread
        char* dst = smraw[buf];
        int k0 = kt * BK;
        bool first = (k0 < E_);
#pragma unroll
        for (int s = 0; s < 4; ++s) {
            const __hip_bfloat16* g = (first ? pA1[s] : pA2[s]) + k0;
            async16(g, dst + s * 8192 + ldsWaveOff);
        }
#pragma unroll
        for (int s = 0; s < 2; ++s) {
            async16(pB0 + (size_t)kt * 8192 + s * 4096, dst + ABYTES + s * 8192 + ldsWaveOff);
        }
    };

    floatx4 acc[4][4];
    floatx4 zero = {0.f, 0.f, 0.f, 0.f};
#pragma unroll
    for (int mi = 0; mi < 4; ++mi)
#pragma unroll
        for (int ni = 0; ni < 4; ++ni) acc[mi][ni] = zero;

    // ---- prologue: stage tiles 0,1 into buf0,buf1; publish tile 0 ----
    stage(0, 0);
    stage(1, 1);
    asm volatile("s_waitcnt vmcnt(6)" ::: "memory");   // tile0 done, tile1 flying
    __builtin_amdgcn_s_barrier();

    for (int kt = 0; kt < NT; ++kt) {
        const int cur = kt % 3;
        const __hip_bfloat16* sm  = (const __hip_bfloat16*)smraw[cur];
        const __hip_bfloat16* smB = sm + ABYTES / 2;

        // ===== phase A (ks=0): issue reads + prefetch-stage, wait after barrier
        {
            int xo = ((quad ^ (lr & 7)) * 8);
            bf16x8 af[4], bfr[4];
#pragma unroll
            for (int mi = 0; mi < 4; ++mi)
                af[mi] = *(const bf16x8*)&sm[(wm + mi * 16 + lr) * 64 + xo];
#pragma unroll
            for (int ni = 0; ni < 4; ++ni)
                bfr[ni] = *(const bf16x8*)&smB[(wn + ni * 16 + lr) * 64 + xo];
            if (kt + 2 < NT) stage(kt + 2, (kt + 2) % 3);
            __builtin_amdgcn_s_barrier();
            asm volatile("s_waitcnt lgkmcnt(0)" ::: "memory");
            __builtin_amdgcn_s_setprio(1);
#pragma unroll
            for (int mi = 0; mi < 4; ++mi)
#pragma unroll
                for (int ni = 0; ni < 4; ++ni)
                    acc[mi][ni] = __builtin_amdgcn_mfma_f32_16x16x32_bf16(
                        af[mi], bfr[ni], acc[mi][ni], 0, 0, 0);
            __builtin_amdgcn_s_setprio(0);
            __builtin_amdgcn_s_barrier();
        }

        // ===== phase B (ks=1)
        {
            int xo = (((4 + quad) ^ (lr & 7)) * 8);
            bf16x8 af[4], bfr[4];
#pragma unroll
            for (int mi = 0; mi < 4; ++mi)
                af[mi] = *(const bf16x8*)&sm[(wm + mi * 16 + lr) * 64 + xo];
#pragma unroll
            for (int ni = 0; ni < 4; ++ni)
                bfr[ni] = *(const bf16x8*)&smB[(wn + ni * 16 + lr) * 64 + xo];
            __builtin_amdgcn_s_barrier();
            asm volatile("s_waitcnt lgkmcnt(0)" ::: "memory");
            __builtin_amdgcn_s_setprio(1);
#pragma unroll
            for (int mi = 0; mi < 4; ++mi)
#pragma unroll
                for (int ni = 0; ni < 4; ++ni)
                    acc[mi][ni] = __builtin_amdgcn_mfma_f32_16x16x32_bf16(
                        af[mi], bfr[ni], acc[mi][ni], 0, 0, 0);
            __builtin_amdgcn_s_setprio(0);
            // publish tile kt+1 (read next iter): counted wait, never 0 mid-loop
            if (kt < NT - 1) {
                if (kt + 2 < NT) { asm volatile("s_waitcnt vmcnt(6)" ::: "memory"); }
                else             { asm volatile("s_waitcnt vmcnt(0)" ::: "memory"); }
            }
            __builtin_amdgcn_s_barrier();
        }
    }

    // ---- epilogue: 4 chunks of 64 rows through LDS sC ----
    float* outH  = out;
    float* outC  = out + (size_t)B_ * T_ * H_;
    float* outHt = out + 2 * (size_t)B_ * T_ * H_;
    float* outCt = outHt + (size_t)B_ * H_;
    auto sC = (float(*)[BN + 4])smraw[0];   // 64 x 132 fp32 = 33792 B

    for (int q = 0; q < 4; ++q) {
        __syncthreads();
        if ((wid & 3) == q) {
#pragma unroll
            for (int mi = 0; mi < 4; ++mi)
#pragma unroll
                for (int ni = 0; ni < 4; ++ni)
#pragma unroll
                    for (int r = 0; r < 4; ++r)
                        sC[mi * 16 + quad * 4 + r][wn + ni * 16 + lr] = acc[mi][ni][r];
        }
        __syncthreads();
#pragma unroll
        for (int s = 0; s < 4; ++s) {
            int p = tid + s * 512;            // 0..2047
            int r  = p >> 5;
            int jj = p & 31;
            float4 v  = *(float4*)&sC[r][jj * 4];
            float4 bb = *(const float4*)&bcat[(size_t)l * ND + nb * BN + jj * 4];
            float u  = sigm(v.x + bb.x);
            float f  = sigm(v.y + bb.y);
            float o  = sigm(v.z + bb.z);
            float ct = tanh_(v.w + bb.w);
            int b = q * 64 + r;
            int j = nb * 32 + jj;
            size_t ci = ((size_t)l * B_ + b) * H_ + j;
            float cn = f * cbuf[ci] + u * ct;
            cbuf[ci] = cn;
            float hn = o * tanh_(cn);
            hwrite[ci] = __float2bfloat16(hn);
            if (l == L_ - 1) {
                size_t oi = ((size_t)b * T_ + t) * H_ + j;
                outH[oi] = hn;
                outC[oi] = cn;
                if (t == T_ - 1) {
                    outHt[(size_t)b * H_ + j] = hn;
                    outCt[(size_t)b * H_ + j] = cn;
                }
            }
        }
    }
}

// ---------------------------------------------------------------------------
extern "C" void kernel_launch(void* const* d_in, const int* in_sizes, int n_in,
                              void* d_out, int out_size, void* d_ws, size_t ws_size,
                              hipStream_t stream)
{
    const float* x   = (const float*)d_in[0];
    const float* h0  = (const float*)d_in[1];
    const float* c0  = (const float*)d_in[2];
    const float* Wu  = (const float*)d_in[3];
    const float* bu  = (const float*)d_in[4];
    const float* Wf  = (const float*)d_in[5];
    const float* bfv = (const float*)d_in[6];
    const float* Wo  = (const float*)d_in[7];
    const float* bo  = (const float*)d_in[8];
    const float* Wc  = (const float*)d_in[9];
    const float* bc  = (const float*)d_in[10];
    float* out = (float*)d_out;

    char* ws = (char*)d_ws;
    __hip_bfloat16* WTt  = (__hip_bfloat16*)(ws);                 // 134217728
    float*          bcat = (float*)(ws + 134217728);              //    131072
    __hip_bfloat16* xbf  = (__hip_bfloat16*)(ws + 134348800);     //   4194304
    __hip_bfloat16* hb0  = (__hip_bfloat16*)(ws + 138543104);     //   4194304
    __hip_bfloat16* hb1  = (__hip_bfloat16*)(ws + 142737408);     //   4194304
    float*          cbuf = (float*)(ws + 146931712);              //   8388608

    hipLaunchKernelGGL(prep_weights_g, dim3(8192), dim3(256), 0, stream, Wu, WTt, 0);
    hipLaunchKernelGGL(prep_weights_g, dim3(8192), dim3(256), 0, stream, Wf, WTt, 1);
    hipLaunchKernelGGL(prep_weights_g, dim3(8192), dim3(256), 0, stream, Wo, WTt, 2);
    hipLaunchKernelGGL(prep_weights_g, dim3(8192), dim3(256), 0, stream, Wc, WTt, 3);
    size_t n2 = (size_t)2097152 * 3 + (size_t)L_ * ND;
    hipLaunchKernelGGL(prep_misc, dim3((unsigned)((n2 + 255) / 256)), dim3(256), 0, stream,
                       x, h0, c0, bu, bfv, bo, bc, xbf, hb0, cbuf, bcat);

    for (int dg = 0; dg <= (T_ - 1) + (L_ - 1); ++dg) {
        int tmin = dg > L_ - 1 ? dg - (L_ - 1) : 0;
        int tmax = dg < T_ - 1 ? dg : T_ - 1;
        int nc = tmax - tmin + 1;
        hipLaunchKernelGGL(lstm_step, dim3(nc * 32), dim3(512), 0, stream,
                           dg, tmin, xbf, WTt, bcat, hb0, hb1, cbuf, out);
    }
}

// Round 5
// 844.153 us; speedup vs baseline: 1.1312x; 1.1312x over previous
//
#include <hip/hip_runtime.h>
#include <hip/hip_bf16.h>

#define B_ 256
#define T_ 8
#define E_ 1024
#define H_ 1024
#define L_ 8
#define KD 2048   // E+H
#define ND 4096   // 4*H, gate-interleaved n = 4*j + g  (g: 0=u,1=f,2=o,3=c~)

#define BM 128
#define BN 128
#define BK 64
// per-buffer LDS: A 128x64 bf16 (16384 B) + B 128x64 bf16 (16384 B)
#define ABYTES 16384
#define BUFBYTES 32768
#define NT (KD / BK)   // 32 K-steps

typedef __bf16 bf16x8 __attribute__((ext_vector_type(8)));
typedef float floatx4 __attribute__((ext_vector_type(4)));

__device__ __forceinline__ float sigm(float x) { return 1.f / (1.f + __expf(-x)); }
__device__ __forceinline__ float tanh_(float x) { return 1.f - 2.f / (__expf(2.f * x) + 1.f); }

__device__ __forceinline__ void async16(const void* g, void* l) {
    __builtin_amdgcn_global_load_lds(
        (const __attribute__((address_space(1))) void*)g,
        (__attribute__((address_space(3))) void*)l, 16, 0, 0);
}

// ---------------------------------------------------------------------------
// P1 (per gate): W_g (L,2048,1024) fp32 -> WTt tiled bf16 layout:
//   WTt[l][nb(32)][kt(32)][row(128)][chunk(8)] , 16B chunks, where chunk slot
//   c stores original k-chunk (c ^ (row&7))  (pre-swizzled for the LDS reader).
// ---------------------------------------------------------------------------
__global__ __launch_bounds__(256) void prep_weights_g(
    const float* __restrict__ src, __hip_bfloat16* __restrict__ WTt, int g)
{
    __shared__ float sm[64][33];
    int bid = blockIdx.x;
    int jt = bid & 31;          // 32 j-tiles of 32
    int kt = (bid >> 5) & 31;   // 32 k-tiles of 64
    int l  = bid >> 10;
    int tid = threadIdx.x;
    int j4  = tid & 7;          // float4 slot in row (8 per 32-float row)
    int kl0 = tid >> 3;         // 0..31
#pragma unroll
    for (int r = 0; r < 2; ++r) {
        int kl = kl0 + r * 32;  // 0..63
        float4 v = *(const float4*)&src[((size_t)(l * KD + kt * 64 + kl)) * 1024 + jt * 32 + j4 * 4];
        sm[kl][j4 * 4 + 0] = v.x;
        sm[kl][j4 * 4 + 1] = v.y;
        sm[kl][j4 * 4 + 2] = v.z;
        sm[kl][j4 * 4 + 3] = v.w;
    }
    __syncthreads();
    int jw = tid >> 3;          // 0..31
    int ch = tid & 7;           // original k-chunk index, kc = ch*8
    int kc = ch * 8;
    bf16x8 v;
#pragma unroll
    for (int i = 0; i < 8; ++i)
        v[i] = (__bf16)sm[kc + i][jw];
    int n   = jt * 32 + jw;     // original column j
    int nn  = n * 4 + g;        // gate-interleaved output row in [0,4096)
    int nb  = nn >> 7;
    int row = nn & 127;
    int cs  = ch ^ (row & 7);   // pre-swizzled chunk slot
    size_t off = ((((size_t)l * 32 + nb) * 32 + kt) * 128 + row) * 64 + (size_t)cs * 8;
    *(bf16x8*)&WTt[off] = v;
}

// ---------------------------------------------------------------------------
// P2: x -> bf16; h0 -> bf16; c0 -> fp32 cbuf; biases -> interleaved bcat
// ---------------------------------------------------------------------------
__global__ __launch_bounds__(256) void prep_misc(
    const float* __restrict__ x,  const float* __restrict__ h0,
    const float* __restrict__ c0,
    const float* __restrict__ bu, const float* __restrict__ bfv,
    const float* __restrict__ bo, const float* __restrict__ bc,
    __hip_bfloat16* __restrict__ xbf, __hip_bfloat16* __restrict__ hb0,
    float* __restrict__ cbuf, float* __restrict__ bcat)
{
    size_t i = (size_t)blockIdx.x * 256 + threadIdx.x;
    const size_t NX = (size_t)B_ * T_ * E_;
    const size_t NH = (size_t)L_ * B_ * H_;
    if (i < NX) {
        xbf[i] = __float2bfloat16(x[i]);
    } else if (i < NX + NH) {
        size_t j = i - NX; hb0[j] = __float2bfloat16(h0[j]);
    } else if (i < NX + 2 * NH) {
        size_t j = i - NX - NH; cbuf[j] = c0[j];
    } else if (i < NX + 2 * NH + (size_t)L_ * ND) {
        size_t j = i - NX - 2 * NH;
        int l = (int)(j >> 12); int n = (int)(j & 4095);
        int jj = n >> 2; int g = n & 3;
        const float* bs = (g == 0) ? bu : (g == 1) ? bfv : (g == 2) ? bo : bc;
        bcat[j] = bs[l * 1024 + jj];
    }
}

// ---------------------------------------------------------------------------
// One diagonal d = t + l. 64 blocks per cell: 2 m-blocks x 32 n-blocks.
// 256 threads = 4 waves (wave grid 2m x 2n, wave tile 64x64 of 16x16x32 MFMA).
// LDS 2 buffers x 32 KB = 64 KB -> 2 blocks/CU at nc=8: independent blocks
// overlap each other's barrier/LDS-burst stalls (m114-style implicit overlap).
// 2 barriers per K-step; counted vmcnt(8) publish, never 0 mid-loop.
// ---------------------------------------------------------------------------
__global__ __launch_bounds__(256) void lstm_step(
    int d, int tmin,
    const __hip_bfloat16* __restrict__ xbf,
    const __hip_bfloat16* __restrict__ WTt,
    const float* __restrict__ bcat,
    __hip_bfloat16* __restrict__ hb0,
    __hip_bfloat16* __restrict__ hb1,
    float* __restrict__ cbuf,
    float* __restrict__ out)
{
    __shared__ __align__(16) char smraw[2][BUFBYTES];   // 65536 B

    int nb   = blockIdx.x & 31;
    int mb   = (blockIdx.x >> 5) & 1;
    int cell = blockIdx.x >> 6;
    int t = tmin + cell;
    int l = d - t;

    const __hip_bfloat16* hread  = (t & 1) ? hb1 : hb0;
    __hip_bfloat16*       hwrite = (t & 1) ? hb0 : hb1;

    const __hip_bfloat16* A1; int sA1;
    if (l == 0) { A1 = xbf + (size_t)t * E_;               sA1 = T_ * E_; }
    else        { A1 = hwrite + (size_t)(l - 1) * B_ * H_; sA1 = H_; }
    const __hip_bfloat16* A2 = hread + (size_t)l * B_ * H_;
    // tiled B panel base: WTt[l][nb][0][0][0]
    const __hip_bfloat16* Bt = WTt + (((size_t)l * 32 + nb) * 32) * 128 * 64;

    int tid  = threadIdx.x;
    int lane = tid & 63;
    int wid  = tid >> 6;           // 0..3
    int wm = (wid & 1) * 64;
    int wn = (wid >> 1) * 64;
    int lr   = lane & 15;
    int quad = lane >> 4;

    // ---- staging address precompute (fixed per thread across K) ----
    int srow = tid >> 3;                      // 0..31
    int c    = (tid & 7) ^ (srow & 7);        // XOR-swizzled 16B-chunk index (A)
    const __hip_bfloat16* pA1[4];
    const __hip_bfloat16* pA2[4];
#pragma unroll
    for (int s = 0; s < 4; ++s) {
        int row = mb * BM + s * 32 + srow;    // global batch row
        pA1[s] = A1 + (size_t)row * sA1 + c * 8;
        pA2[s] = A2 + (size_t)row * H_ + c * 8 - E_;
    }
    // B: linear stream within tile; per-thread fixed offset tid*16 bytes
    const __hip_bfloat16* pB0 = Bt + (size_t)tid * 8;
    int ldsWaveOff = wid << 10;               // wid*1024 bytes

    auto stage = [&](int kt, int buf) {       // 8 global_load_lds per thread
        char* dst = smraw[buf];
        int k0 = kt * BK;
        bool first = (k0 < E_);
#pragma unroll
        for (int s = 0; s < 4; ++s) {
            const __hip_bfloat16* g = (first ? pA1[s] : pA2[s]) + k0;
            async16(g, dst + s * 4096 + ldsWaveOff);
        }
#pragma unroll
        for (int s = 0; s < 4; ++s) {
            async16(pB0 + (size_t)kt * 8192 + s * 2048,
                    dst + ABYTES + s * 4096 + ldsWaveOff);
        }
    };

    floatx4 acc[4][4];
    floatx4 zero = {0.f, 0.f, 0.f, 0.f};
#pragma unroll
    for (int mi = 0; mi < 4; ++mi)
#pragma unroll
        for (int ni = 0; ni < 4; ++ni) acc[mi][ni] = zero;

    // ---- prologue: stage tiles 0,1; publish tile 0 (8 of tile1 in flight) ----
    stage(0, 0);
    stage(1, 1);
    asm volatile("s_waitcnt vmcnt(8)" ::: "memory");
    __builtin_amdgcn_s_barrier();

    for (int kt = 0; kt < NT; ++kt) {
        const __hip_bfloat16* sm  = (const __hip_bfloat16*)smraw[kt & 1];
        const __hip_bfloat16* smB = sm + ABYTES / 2;   // elements

#pragma unroll
        for (int ks = 0; ks < 2; ++ks) {
            int xo = (((ks * 4 + quad) ^ (lr & 7)) * 8);   // element offset in row
            bf16x8 af[4], bfr[4];
#pragma unroll
            for (int mi = 0; mi < 4; ++mi)
                af[mi] = *(const bf16x8*)&sm[(wm + mi * 16 + lr) * 64 + xo];
#pragma unroll
            for (int ni = 0; ni < 4; ++ni)
                bfr[ni] = *(const bf16x8*)&smB[(wn + ni * 16 + lr) * 64 + xo];
            asm volatile("s_waitcnt lgkmcnt(0)" ::: "memory");
            __builtin_amdgcn_sched_barrier(0);
            __builtin_amdgcn_s_setprio(1);
#pragma unroll
            for (int mi = 0; mi < 4; ++mi)
#pragma unroll
                for (int ni = 0; ni < 4; ++ni)
                    acc[mi][ni] = __builtin_amdgcn_mfma_f32_16x16x32_bf16(
                        af[mi], bfr[ni], acc[mi][ni], 0, 0, 0);
            __builtin_amdgcn_s_setprio(0);
        }

        // all waves done reading buf[kt&1] -> safe to re-target its DMA
        __builtin_amdgcn_s_barrier();
        if (kt + 2 < NT) stage(kt + 2, kt & 1);
        if (kt < NT - 1) {
            // publish buf[(kt+1)&1]: its 8 loads (issued last iter) must land;
            // keep the 8 just-issued loads in flight.
            if (kt + 2 < NT) { asm volatile("s_waitcnt vmcnt(8)" ::: "memory"); }
            else             { asm volatile("s_waitcnt vmcnt(0)" ::: "memory"); }
            __builtin_amdgcn_s_barrier();
        }
    }

    // ---- epilogue: 2 chunks of 64 rows through LDS sC ----
    float* outH  = out;
    float* outC  = out + (size_t)B_ * T_ * H_;
    float* outHt = out + 2 * (size_t)B_ * T_ * H_;
    float* outCt = outHt + (size_t)B_ * H_;
    auto sC = (float(*)[BN + 4])smraw[0];   // 64 x 132 fp32 = 33792 B

    for (int q = 0; q < 2; ++q) {
        __syncthreads();
        if ((wid & 1) == q) {
#pragma unroll
            for (int mi = 0; mi < 4; ++mi)
#pragma unroll
                for (int ni = 0; ni < 4; ++ni)
#pragma unroll
                    for (int r = 0; r < 4; ++r)
                        sC[mi * 16 + quad * 4 + r][wn + ni * 16 + lr] = acc[mi][ni][r];
        }
        __syncthreads();
#pragma unroll
        for (int s = 0; s < 8; ++s) {
            int p = tid + s * 256;            // 0..2047
            int r  = p >> 5;
            int jj = p & 31;
            float4 v  = *(float4*)&sC[r][jj * 4];
            float4 bb = *(const float4*)&bcat[(size_t)l * ND + nb * BN + jj * 4];
            float u  = sigm(v.x + bb.x);
            float f  = sigm(v.y + bb.y);
            float o  = sigm(v.z + bb.z);
            float ct = tanh_(v.w + bb.w);
            int b = mb * BM + q * 64 + r;
            int j = nb * 32 + jj;
            size_t ci = ((size_t)l * B_ + b) * H_ + j;
            float cn = f * cbuf[ci] + u * ct;
            cbuf[ci] = cn;
            float hn = o * tanh_(cn);
            hwrite[ci] = __float2bfloat16(hn);
            if (l == L_ - 1) {
                size_t oi = ((size_t)b * T_ + t) * H_ + j;
                outH[oi] = hn;
                outC[oi] = cn;
                if (t == T_ - 1) {
                    outHt[(size_t)b * H_ + j] = hn;
                    outCt[(size_t)b * H_ + j] = cn;
                }
            }
        }
    }
}

// ---------------------------------------------------------------------------
extern "C" void kernel_launch(void* const* d_in, const int* in_sizes, int n_in,
                              void* d_out, int out_size, void* d_ws, size_t ws_size,
                              hipStream_t stream)
{
    const float* x   = (const float*)d_in[0];
    const float* h0  = (const float*)d_in[1];
    const float* c0  = (const float*)d_in[2];
    const float* Wu  = (const float*)d_in[3];
    const float* bu  = (const float*)d_in[4];
    const float* Wf  = (const float*)d_in[5];
    const float* bfv = (const float*)d_in[6];
    const float* Wo  = (const float*)d_in[7];
    const float* bo  = (const float*)d_in[8];
    const float* Wc  = (const float*)d_in[9];
    const float* bc  = (const float*)d_in[10];
    float* out = (float*)d_out;

    char* ws = (char*)d_ws;
    __hip_bfloat16* WTt  = (__hip_bfloat16*)(ws);                 // 134217728
    float*          bcat = (float*)(ws + 134217728);              //    131072
    __hip_bfloat16* xbf  = (__hip_bfloat16*)(ws + 134348800);     //   4194304
    __hip_bfloat16* hb0  = (__hip_bfloat16*)(ws + 138543104);     //   4194304
    __hip_bfloat16* hb1  = (__hip_bfloat16*)(ws + 142737408);     //   4194304
    float*          cbuf = (float*)(ws + 146931712);              //   8388608

    hipLaunchKernelGGL(prep_weights_g, dim3(8192), dim3(256), 0, stream, Wu, WTt, 0);
    hipLaunchKernelGGL(prep_weights_g, dim3(8192), dim3(256), 0, stream, Wf, WTt, 1);
    hipLaunchKernelGGL(prep_weights_g, dim3(8192), dim3(256), 0, stream, Wo, WTt, 2);
    hipLaunchKernelGGL(prep_weights_g, dim3(8192), dim3(256), 0, stream, Wc, WTt, 3);
    size_t n2 = (size_t)2097152 * 3 + (size_t)L_ * ND;
    hipLaunchKernelGGL(prep_misc, dim3((unsigned)((n2 + 255) / 256)), dim3(256), 0, stream,
                       x, h0, c0, bu, bfv, bo, bc, xbf, hb0, cbuf, bcat);

    for (int dg = 0; dg <= (T_ - 1) + (L_ - 1); ++dg) {
        int tmin = dg > L_ - 1 ? dg - (L_ - 1) : 0;
        int tmax = dg < T_ - 1 ? dg : T_ - 1;
        int nc = tmax - tmin + 1;
        hipLaunchKernelGGL(lstm_step, dim3(nc * 64), dim3(256), 0, stream,
                           dg, tmin, xbf, WTt, bcat, hb0, hb1, cbuf, out);
    }
}